// Round 18
// baseline (3992.113 us; speedup 1.0000x reference)
//
#include <hip/hip_runtime.h>

#define N_NODESC 20000
#define N_EDGESC 640000

typedef _Float16 f16;
typedef __attribute__((ext_vector_type(4))) _Float16 f16x4;
typedef __attribute__((ext_vector_type(8))) _Float16 f16x8;
typedef __attribute__((ext_vector_type(4))) float f32x4;

__device__ __forceinline__ f32x4 mfma16(f16x8 a, f16x8 b, f32x4 c){
  return __builtin_amdgcn_mfma_f32_16x16x32_f16(a, b, c, 0, 0, 0);
}
__device__ __forceinline__ float sigm(float x){ return 1.f/(1.f+__expf(-x)); }
__device__ __forceinline__ float tanh_(float x){
  x = fminf(fmaxf(x, -15.f), 15.f);
  float e = __expf(-2.f*x);
  return (1.f - e)/(1.f + e);
}
__device__ __forceinline__ void stage16(const void* g, void* l){
  __builtin_amdgcn_global_load_lds((const __attribute__((address_space(1))) unsigned int*)g,
                                   (__attribute__((address_space(3))) unsigned int*)l, 16, 0, 0);
}
#define SB       __builtin_amdgcn_sched_barrier(0)
#define AS_VM(n) do{ asm volatile("s_waitcnt vmcnt(" #n ")" ::: "memory"); SB; }while(0)
#define BAR      do{ __builtin_amdgcn_s_barrier(); SB; }while(0)

// ---------------- CSR construction ----------------
__global__ __launch_bounds__(256) void k_hist(const int* __restrict__ dst, int* __restrict__ cnt){
  int e = blockIdx.x*256 + threadIdx.x;
  if(e < N_EDGESC) atomicAdd(&cnt[dst[e]], 1);
}

__global__ __launch_bounds__(256) void k_scanA(const int* __restrict__ cnt,
    int* __restrict__ row_ptr, int* __restrict__ btot){
  __shared__ int ws[4];
  int b = blockIdx.x, t = threadIdx.x;
  int i = b*256 + t;
  int v = (i < N_NODESC) ? cnt[i] : 0;
  int lane = t&63, wv = t>>6;
  int incl = v;
  #pragma unroll
  for(int off=1; off<64; off<<=1){ int u = __shfl_up(incl, off); if(lane>=off) incl += u; }
  if(lane==63) ws[wv] = incl;
  __syncthreads();
  int woff = 0;
  for(int k=0;k<wv;k++) woff += ws[k];
  if(i < N_NODESC) row_ptr[i] = woff + incl - v;
  if(t == 255) btot[b] = woff + incl;
}

__global__ __launch_bounds__(128) void k_scanB(const int* __restrict__ btot,
    int* __restrict__ boff, int* __restrict__ row_ptr){
  __shared__ int s[128];
  int t = threadIdx.x;
  int orig = (t < 79) ? btot[t] : 0;
  s[t] = orig;
  __syncthreads();
  #pragma unroll
  for(int off=1; off<128; off<<=1){
    int u = (t>=off) ? s[t-off] : 0;
    __syncthreads();
    s[t] += u;
    __syncthreads();
  }
  if(t < 79) boff[t] = s[t] - orig;
  if(t == 0) row_ptr[N_NODESC] = N_EDGESC;
}

__global__ __launch_bounds__(256) void k_scanC(const int* __restrict__ cnt,
    const int* __restrict__ boff, int* __restrict__ row_ptr,
    float* __restrict__ deg_inv, float* __restrict__ deg_is){
  int i = blockIdx.x*256 + threadIdx.x;
  if(i >= N_NODESC) return;
  row_ptr[i] += boff[blockIdx.x];
  float d = (float)(cnt[i] + 1);
  deg_inv[i] = 1.f/d;
  deg_is[i]  = rsqrtf(d);
}

__global__ __launch_bounds__(256) void k_fill(const int* __restrict__ src, const int* __restrict__ dst,
    const int* __restrict__ row_ptr, int* __restrict__ cursor, const float* __restrict__ deg_is,
    int2* __restrict__ ev){
  int e = blockIdx.x*256 + threadIdx.x;
  if(e >= N_EDGESC) return;
  int d = dst[e], s = src[e];
  int p = atomicAdd(&cursor[d], 1);
  int2 v;
  v.x = s;
  v.y = __float_as_int(deg_is[s]*deg_is[d]);
  ev[row_ptr[d] + p] = v;
}

__global__ __launch_bounds__(256) void k_cvt(const float* __restrict__ x, f16* __restrict__ o, int n4){
  int i = blockIdx.x*256 + threadIdx.x;
  if(i >= n4) return;
  f32x4 v = *(const f32x4*)(x + (size_t)i*4);
  *(f16x4*)(o + (size_t)i*4) = __builtin_convertvector(v, f16x4);
}

// weight packing: Bp[((kb*NO + c)*4 + g)*8 + i] = B[k = kb*32 + g*8 + i][c]
__global__ __launch_bounds__(256) void k_pack(const float* __restrict__ w, f16* __restrict__ dstp,
    int K, int NO, int trans){
  int t = blockIdx.x*256 + threadIdx.x;
  if(t >= K*NO) return;
  int i = t&7, g = (t>>3)&3, rest = t>>5;
  int c = rest % NO, kb = rest / NO;
  int k = kb*32 + g*8 + i;
  float v = trans ? w[(size_t)c*K + k] : w[(size_t)k*NO + c];
  dstp[t] = (f16)v;
}

// ---------------- aggregation ----------------
__global__ __launch_bounds__(256) void k_agg64(const f16* __restrict__ x,
    const int* __restrict__ row_ptr, const int2* __restrict__ ev,
    const float* __restrict__ deg_inv, f16* __restrict__ O){
  int n = (blockIdx.x*256 + threadIdx.x)>>6;
  int c = threadIdx.x&63;
  if(n >= N_NODESC) return;
  float acc = deg_inv[n]*(float)x[(size_t)n*64 + c];
  int e0 = row_ptr[n], e1 = row_ptr[n+1];
  int e = e0;
  for(; e+4<=e1; e+=4){
    int2 a=ev[e], b=ev[e+1], cc=ev[e+2], d=ev[e+3];
    float v0=(float)x[(size_t)a.x*64+c],  v1=(float)x[(size_t)b.x*64+c];
    float v2=(float)x[(size_t)cc.x*64+c], v3=(float)x[(size_t)d.x*64+c];
    acc += __int_as_float(a.y)*v0 + __int_as_float(b.y)*v1
         + __int_as_float(cc.y)*v2 + __int_as_float(d.y)*v3;
  }
  for(; e<e1; e++){ int2 a=ev[e]; acc += __int_as_float(a.y)*(float)x[(size_t)a.x*64+c]; }
  O[(size_t)n*64+c] = (f16)acc;
}

// agg256 v2: channel-split (4 groups x 64ch), XCD-pair-pinned.
// grid 20000: xcd=b&7 -> group g=xcd>>1 (pinned to XCD pair), node-chunk local=(b>>3)*2+(b&1).
// Per-XCD gather footprint = 20000 rows x 128B = 2.5MB < 4MB L2 -> local hits.
__global__ __launch_bounds__(256) void k_agg256(const f16* __restrict__ x1,
    const int* __restrict__ row_ptr, const int2* __restrict__ ev,
    const float* __restrict__ deg_inv, f16* __restrict__ O){
  const int b = blockIdx.x;
  const int xcd = b & 7;
  const int g = xcd >> 1;
  const int local = (b >> 3)*2 + (xcd & 1);     // 0..4999
  const int n = local*4 + (threadIdx.x>>6);
  const int lane = threadIdx.x & 63;
  if(n >= N_NODESC) return;
  const int coff = g*64 + lane;
  float acc = deg_inv[n]*(float)x1[(size_t)n*256 + coff];
  int e0 = row_ptr[n], e1 = row_ptr[n+1];
  int e = e0;
  for(; e+4<=e1; e+=4){
    int2 a=ev[e], b2=ev[e+1], c2=ev[e+2], d2=ev[e+3];
    float v0=(float)x1[(size_t)a.x*256+coff],  v1=(float)x1[(size_t)b2.x*256+coff];
    float v2=(float)x1[(size_t)c2.x*256+coff], v3=(float)x1[(size_t)d2.x*256+coff];
    acc += __int_as_float(a.y)*v0 + __int_as_float(b2.y)*v1
         + __int_as_float(c2.y)*v2 + __int_as_float(d2.y)*v3;
  }
  for(; e<e1; e++){ int2 a=ev[e]; acc += __int_as_float(a.y)*(float)x1[(size_t)a.x*256+coff]; }
  O[(size_t)n*256+coff] = (f16)acc;
}

// =============== coalesced + swizzled resident-tile GEMM kernels (R15/R17 winners) ===============
// LDS per plane: [row][32 slots x 16B]; global chunk c at slot s = c ^ (row&7).
// A-frag read (r, kb, q): addr = r*512 + ((kb*4+q)^(l15&7))*16.

// ---------------- GCN1: K=64 (128B rows), N=256 ----------------
__global__ __launch_bounds__(256) void k_gcn1(const f16* __restrict__ A,
    const f16* __restrict__ Bp, const float* __restrict__ bias, f16* __restrict__ C){
  __shared__ f16x8 ldsv[512];                  // 8KB
  char* lds = (char*)ldsv;
  const int tid = threadIdx.x, lane = tid&63, w = tid>>6, l15 = lane&15, q = lane>>4;
  const int m0 = blockIdx.x*64;
  #pragma unroll
  for(int i=0;i<2;i++){
    const int o = i*4096 + tid*16;
    const int row = o>>7, s = (o>>4)&7;
    const int c = s ^ (row&7);
    int rgs = m0 + row; if(rgs > N_NODESC-1) rgs = N_NODESC-1;
    stage16((const char*)A + (size_t)rgs*128 + c*16, lds + o);
  }
  AS_VM(0);
  BAR;
  f32x4 acc[4][4];
  #pragma unroll
  for(int rt=0;rt<4;rt++)
    #pragma unroll
    for(int ct=0;ct<4;ct++) acc[rt][ct] = (f32x4){0.f,0.f,0.f,0.f};
  const int l7 = l15&7;
  #pragma unroll
  for(int kb=0;kb<2;kb++){
    f16x8 bf[4];
    #pragma unroll
    for(int ct=0;ct<4;ct++){
      int c = w*64 + ct*16 + l15;
      bf[ct] = *(const f16x8*)(Bp + ((unsigned)(kb*256 + c)*4 + q)*8);
    }
    const int swz = ((kb*4+q) ^ l7)<<4;
    #pragma unroll
    for(int rt=0;rt<4;rt++){
      f16x8 ah = *(const f16x8*)(lds + (rt*16+l15)*128 + swz);
      #pragma unroll
      for(int ct=0;ct<4;ct++)
        acc[rt][ct] = mfma16(ah, bf[ct], acc[rt][ct]);
    }
  }
  #pragma unroll
  for(int rt=0;rt<4;rt++)
    #pragma unroll
    for(int ct=0;ct<4;ct++){
      int c = w*64 + ct*16 + l15;
      float bv = bias[c];
      #pragma unroll
      for(int j=0;j<4;j++){
        int r = m0 + rt*16 + q*4 + j;
        if(r < N_NODESC) C[(size_t)r*256 + c] = (f16)fmaxf(acc[rt][ct][j] + bv, 0.f);
      }
    }
}

// ---------------- GCN2: 256-thr, A resident (32KB), dist-2 B ----------
__global__ __launch_bounds__(256,3) void k_gcn2(const f16* __restrict__ A,
    const f16* __restrict__ Bp, const float* __restrict__ bias, f16* __restrict__ C){
  __shared__ f16x8 ldsv[2048];                 // 32KB
  char* lds = (char*)ldsv;
  const int tid = threadIdx.x, lane = tid&63, w = tid>>6, l15 = lane&15, q = lane>>4;
  const int m0 = blockIdx.x*64;
  #pragma unroll
  for(int i=0;i<8;i++){
    const int o = i*4096 + tid*16;
    const int row = o>>9, s = (o>>4)&31;
    const int c = s ^ (row&7);
    int rgs = m0 + row; if(rgs > N_NODESC-1) rgs = N_NODESC-1;
    stage16((const char*)A + (size_t)rgs*512 + c*16, lds + o);
  }
  f32x4 acc[4][4];
  #pragma unroll
  for(int rt=0;rt<4;rt++)
    #pragma unroll
    for(int ct=0;ct<4;ct++) acc[rt][ct] = (f32x4){0.f,0.f,0.f,0.f};
  f16x8 bf[3][4];
  const int cbase = w*64 + l15;
  #pragma unroll
  for(int s=0;s<2;s++)
    #pragma unroll
    for(int ct=0;ct<4;ct++)
      bf[s][ct] = *(const f16x8*)(Bp + ((unsigned)(s*256 + cbase + ct*16)*4 + q)*8);
  AS_VM(0);
  BAR;
  const int l7 = l15&7;
  #pragma unroll
  for(int kb=0;kb<8;kb++){
    const int s = kb%3;
    if(kb<6){
      const int ns = (kb+2)%3;
      #pragma unroll
      for(int ct=0;ct<4;ct++)
        bf[ns][ct] = *(const f16x8*)(Bp + ((unsigned)((kb+2)*256 + cbase + ct*16)*4 + q)*8);
    }
    const int swz = ((kb*4+q) ^ l7)<<4;
    __builtin_amdgcn_s_setprio(1);
    #pragma unroll
    for(int rt=0;rt<4;rt++){
      f16x8 ah = *(const f16x8*)(lds + (rt*16+l15)*512 + swz);
      #pragma unroll
      for(int ct=0;ct<4;ct++)
        acc[rt][ct] = mfma16(ah, bf[s][ct], acc[rt][ct]);
    }
    __builtin_amdgcn_s_setprio(0);
  }
  #pragma unroll
  for(int rt=0;rt<4;rt++)
    #pragma unroll
    for(int ct=0;ct<4;ct++){
      int c = cbase + ct*16;
      float bv = bias[c];
      #pragma unroll
      for(int j=0;j<4;j++){
        int r = m0 + rt*16 + q*4 + j;
        if(r < N_NODESC) C[(size_t)r*256 + c] = (f16)fmaxf(acc[rt][ct][j] + bv, 0.f);
      }
    }
}

// ---------------- fused GRU v13: R15 structure (256-thr) + ZH template ----------
template<int ZH>
__global__ __launch_bounds__(256,2) void k_gru(
    const f16* __restrict__ X, const f16* __restrict__ H, f16* __restrict__ Nh,
    const f16* __restrict__ Wi, const f16* __restrict__ Wh,
    const float* __restrict__ bih, const float* __restrict__ bhh){
  __shared__ f16x8 ldsv[4096];                 // 64KB: 2 planes x [row:64][32x16B]
  char* lds = (char*)ldsv;
  const int NB = 1252, QQ = NB>>3, RR = NB&7;  // 156, 4
  int bid = blockIdx.x;
  int xcd = bid & 7, jj = bid >> 3;
  int nid = (xcd < RR) ? xcd*(QQ+1) + jj : RR*(QQ+1) + (xcd-RR)*QQ + jj;
  const int m0 = (nid>>2)*64;
  const int cb = nid&3;
  const int tid = threadIdx.x, lane = tid&63, w = tid>>6, l15 = lane&15, q = lane>>4;
  const int cc = cb*64 + w*16 + l15;
  const f16* pl[2] = {X, H};
  #pragma unroll
  for(int i=0;i<(ZH?8:16);i++){
    const int o = i*4096 + tid*16;
    const int p = o>>15;
    const int rem = o & 32767;
    const int row = rem>>9, s = (rem>>4)&31;
    const int c = s ^ (row&7);
    int rgs = m0 + row; if(rgs > N_NODESC-1) rgs = N_NODESC-1;
    stage16((const char*)pl[p] + (size_t)rgs*512 + c*16, lds + o);
  }
  f32x4 acc[6][4];
  #pragma unroll
  for(int m=0;m<6;m++)
    #pragma unroll
    for(int rt=0;rt<4;rt++) acc[m][rt] = (f32x4){0.f,0.f,0.f,0.f};
  const unsigned wbase = (unsigned)cc*32 + q*8;   // f16 units; +gate*8192 +kb*24576
  f16x8 bi[3][3], bh[3][3];                       // ring: slot = kb%3
  #pragma unroll
  for(int s=0;s<2;s++){
    unsigned wo = wbase + (unsigned)s*24576u;
    bi[s][0] = *(const f16x8*)(Wi + wo);
    bi[s][1] = *(const f16x8*)(Wi + wo + 8192);
    bi[s][2] = *(const f16x8*)(Wi + wo + 16384);
    if(!ZH){
      bh[s][0] = *(const f16x8*)(Wh + wo);
      bh[s][1] = *(const f16x8*)(Wh + wo + 8192);
      bh[s][2] = *(const f16x8*)(Wh + wo + 16384);
    }
  }
  AS_VM(0);
  BAR;
  const int l7 = l15&7;
  #pragma unroll
  for(int kb=0;kb<8;kb++){
    const int s = kb%3;
    if(kb<6){
      const int ns = (kb+2)%3;
      unsigned wo = wbase + (unsigned)(kb+2)*24576u;
      bi[ns][0] = *(const f16x8*)(Wi + wo);
      bi[ns][1] = *(const f16x8*)(Wi + wo + 8192);
      bi[ns][2] = *(const f16x8*)(Wi + wo + 16384);
      if(!ZH){
        bh[ns][0] = *(const f16x8*)(Wh + wo);
        bh[ns][1] = *(const f16x8*)(Wh + wo + 8192);
        bh[ns][2] = *(const f16x8*)(Wh + wo + 16384);
      }
    }
    const int swz = ((kb*4+q) ^ l7)<<4;
    __builtin_amdgcn_s_setprio(1);
    #pragma unroll
    for(int rt=0;rt<4;rt++){
      const int ro = (rt*16+l15)*512 + swz;
      f16x8 ax = *(const f16x8*)(lds + ro);
      acc[0][rt] = mfma16(ax, bi[s][0], acc[0][rt]);
      acc[1][rt] = mfma16(ax, bi[s][1], acc[1][rt]);
      acc[2][rt] = mfma16(ax, bi[s][2], acc[2][rt]);
      if(!ZH){
        f16x8 ah = *(const f16x8*)(lds + 32768 + ro);
        acc[3][rt] = mfma16(ah, bh[s][0], acc[3][rt]);
        acc[4][rt] = mfma16(ah, bh[s][1], acc[4][rt]);
        acc[5][rt] = mfma16(ah, bh[s][2], acc[5][rt]);
      }
    }
    __builtin_amdgcn_s_setprio(0);
  }
  float bir=bih[cc], biz=bih[cc+256], bin=bih[cc+512];
  float bhr=bhh[cc], bhz=bhh[cc+256], bhn=bhh[cc+512];
  const int hcc = (cc>>3);
  const int hlo = (cc&7)*2;
  #pragma unroll
  for(int rt=0;rt<4;rt++){
    #pragma unroll
    for(int j=0;j<4;j++){
      int r = rt*16 + q*4 + j;
      int grow = m0 + r;
      if(grow < N_NODESC){
        float ir=acc[0][rt][j], iz=acc[1][rt][j], in_=acc[2][rt][j];
        float hr = ZH ? 0.f : acc[3][rt][j];
        float hz = ZH ? 0.f : acc[4][rt][j];
        float hn = ZH ? 0.f : acc[5][rt][j];
        float rgt = sigm(ir+bir + hr+bhr);
        float zg = sigm(iz+biz + hz+bhz);
        float ng = tanh_(in_+bin + rgt*(hn+bhn));
        float ho = ZH ? 0.f
          : (float)*(const f16*)(lds + 32768 + r*512 + ((hcc ^ (r&7))<<4) + hlo);
        float v = (1.f-zg)*ng + zg*ho;
        Nh[(size_t)grow*256 + cc] = (f16)v;
      }
    }
  }
}

// ---------------- projection: A resident (32KB), dist-2 B; f32 out + f16 feedback ----------
__global__ __launch_bounds__(256,4) void k_proj(const f16* __restrict__ A,
    const f16* __restrict__ Bp, const float* __restrict__ bias,
    float* __restrict__ C, f16* __restrict__ Cf16){
  __shared__ f16x8 ldsv[2048];                 // 32KB
  char* lds = (char*)ldsv;
  const int tid = threadIdx.x, lane = tid&63, w = tid>>6, l15 = lane&15, q = lane>>4;
  const int m0 = blockIdx.x*64;
  const int cc = w*16 + l15;
  #pragma unroll
  for(int i=0;i<8;i++){
    const int o = i*4096 + tid*16;
    const int row = o>>9, s = (o>>4)&31;
    const int c = s ^ (row&7);
    int rgs = m0 + row; if(rgs > N_NODESC-1) rgs = N_NODESC-1;
    stage16((const char*)A + (size_t)rgs*512 + c*16, lds + o);
  }
  f32x4 acc[4];
  #pragma unroll
  for(int rt=0;rt<4;rt++) acc[rt] = (f32x4){0.f,0.f,0.f,0.f};
  f16x8 bf[3];
  bf[0] = *(const f16x8*)(Bp + ((unsigned)(0*64 + cc)*4 + q)*8);
  bf[1] = *(const f16x8*)(Bp + ((unsigned)(1*64 + cc)*4 + q)*8);
  AS_VM(0);
  BAR;
  const int l7 = l15&7;
  #pragma unroll
  for(int kb=0;kb<8;kb++){
    const int s = kb%3;
    if(kb<6)
      bf[(kb+2)%3] = *(const f16x8*)(Bp + ((unsigned)((kb+2)*64 + cc)*4 + q)*8);
    const int swz = ((kb*4+q) ^ l7)<<4;
    #pragma unroll
    for(int rt=0;rt<4;rt++){
      f16x8 ah = *(const f16x8*)(lds + (rt*16+l15)*512 + swz);
      acc[rt] = mfma16(ah, bf[s], acc[rt]);
    }
  }
  #pragma unroll
  for(int rt=0;rt<4;rt++){
    float bv = bias[cc];
    #pragma unroll
    for(int j=0;j<4;j++){
      int r = m0 + rt*16 + q*4 + j;
      if(r < N_NODESC){
        float v = acc[rt][j] + bv;
        C[(size_t)r*64 + cc] = v;
        Cf16[(size_t)r*64 + cc] = (f16)v;
      }
    }
  }
}

// ---------------- launcher ----------------
extern "C" void kernel_launch(void* const* d_in, const int* in_sizes, int n_in,
                              void* d_out, int out_size, void* d_ws, size_t ws_size,
                              hipStream_t stream){
  const float* x_seq  = (const float*)d_in[0];
  const int*   srcp   = (const int*)  d_in[1];
  const int*   dstp   = (const int*)  d_in[2];
  const float* gcn1_w = (const float*)d_in[3];
  const float* gcn1_b = (const float*)d_in[4];
  const float* gcn2_w = (const float*)d_in[5];
  const float* gcn2_b = (const float*)d_in[6];
  const float* proj_w = (const float*)d_in[7];
  const float* proj_b = (const float*)d_in[8];
  const float* wih[3] = {(const float*)d_in[9],  (const float*)d_in[13], (const float*)d_in[17]};
  const float* whh[3] = {(const float*)d_in[10], (const float*)d_in[14], (const float*)d_in[18]};
  const float* bih[3] = {(const float*)d_in[11], (const float*)d_in[15], (const float*)d_in[19]};
  const float* bhh[3] = {(const float*)d_in[12], (const float*)d_in[16], (const float*)d_in[20]};
  float* out = (float*)d_out;

  const size_t NP = (size_t)N_NODESC*256;
  char* p = (char*)d_ws;
  auto alloc = [&](size_t bytes)->char*{ char* r = p; p += (bytes + 255) & ~(size_t)255; return r; };
  int*   deg_cnt = (int*)  alloc((size_t)2*N_NODESC*4);
  int*   cursor  = deg_cnt + N_NODESC;
  int*   row_ptr = (int*)  alloc((size_t)(N_NODESC+1)*4);
  float* deg_inv = (float*)alloc((size_t)N_NODESC*4);
  float* deg_is  = (float*)alloc((size_t)N_NODESC*4);
  int*   btot    = (int*)  alloc((size_t)128*4);
  int*   boff    = (int*)  alloc((size_t)128*4);
  int2*  ev      = (int2*) alloc((size_t)N_EDGESC*8);
  f16* xf16 = (f16*)alloc((size_t)12*N_NODESC*64*2);
  f16* xdec = (f16*)alloc((size_t)N_NODESC*64*2);
  f16* z64  = (f16*)alloc((size_t)N_NODESC*64*2);
  f16* x1   = (f16*)alloc(NP*2);
  f16* xa   = (f16*)alloc(NP*2);
  f16* hbuf = (f16*)alloc((size_t)2*3*NP*2);     // [slot][gru][N*256] — no memset (ZH path)
  f16* pk_gcn1 = (f16*)alloc((size_t)64*256*2);
  f16* pk_gcn2 = (f16*)alloc((size_t)256*256*2);
  f16* pk_proj = (f16*)alloc((size_t)256*64*2);
  f16* pk_wi[3]; f16* pk_wh[3];
  for(int i=0;i<3;i++){ pk_wi[i]=(f16*)alloc((size_t)256*768*2); pk_wh[i]=(f16*)alloc((size_t)256*768*2); }

  hipMemsetAsync(deg_cnt, 0, (size_t)2*N_NODESC*4, stream);

  k_hist <<<2500,256,0,stream>>>(dstp, deg_cnt);
  k_scanA<<<79,  256,0,stream>>>(deg_cnt, row_ptr, btot);
  k_scanB<<<1,   128,0,stream>>>(btot, boff, row_ptr);
  k_scanC<<<79,  256,0,stream>>>(deg_cnt, boff, row_ptr, deg_inv, deg_is);
  k_fill <<<2500,256,0,stream>>>(srcp, dstp, row_ptr, cursor, deg_is, ev);
  k_cvt  <<<15000,256,0,stream>>>(x_seq, xf16, 12*N_NODESC*64/4);

  k_pack<<<64, 256,0,stream>>>(gcn1_w, pk_gcn1, 64, 256, 0);
  k_pack<<<256,256,0,stream>>>(gcn2_w, pk_gcn2, 256,256, 0);
  k_pack<<<64, 256,0,stream>>>(proj_w, pk_proj, 256, 64, 0);
  for(int i=0;i<3;i++){
    k_pack<<<768,256,0,stream>>>(wih[i], pk_wi[i], 256, 768, 1);
    k_pack<<<768,256,0,stream>>>(whh[i], pk_wh[i], 256, 768, 1);
  }

  auto Hs = [&](int slot, int g)->f16*{ return hbuf + ((size_t)(slot*3+g))*NP; };

  for(int s=0; s<18; s++){
    const f16* xt;
    if(s < 12)       xt = xf16 + (size_t)s*N_NODESC*64;
    else if(s == 12) xt = xf16 + (size_t)11*N_NODESC*64;
    else             xt = xdec;
    int cur = s&1, nxt = cur^1;

    k_agg64 <<<5000,256,0,stream>>>(xt, row_ptr, ev, deg_inv, z64);
    k_gcn1  <<<313, 256,0,stream>>>(z64, pk_gcn1, gcn1_b, x1);
    k_agg256<<<20000,256,0,stream>>>(x1, row_ptr, ev, deg_inv, xa);
    k_gcn2  <<<313, 256,0,stream>>>(xa, pk_gcn2, gcn2_b, xa);

    if(s == 0){
      k_gru<1><<<1252,256,0,stream>>>(xa,        Hs(cur,0), Hs(nxt,0), pk_wi[0], pk_wh[0], bih[0], bhh[0]);
      k_gru<1><<<1252,256,0,stream>>>(Hs(nxt,0), Hs(cur,1), Hs(nxt,1), pk_wi[1], pk_wh[1], bih[1], bhh[1]);
      k_gru<1><<<1252,256,0,stream>>>(Hs(nxt,1), Hs(cur,2), Hs(nxt,2), pk_wi[2], pk_wh[2], bih[2], bhh[2]);
    } else {
      k_gru<0><<<1252,256,0,stream>>>(xa,        Hs(cur,0), Hs(nxt,0), pk_wi[0], pk_wh[0], bih[0], bhh[0]);
      k_gru<0><<<1252,256,0,stream>>>(Hs(nxt,0), Hs(cur,1), Hs(nxt,1), pk_wi[1], pk_wh[1], bih[1], bhh[1]);
      k_gru<0><<<1252,256,0,stream>>>(Hs(nxt,1), Hs(cur,2), Hs(nxt,2), pk_wi[2], pk_wh[2], bih[2], bhh[2]);
    }

    if(s >= 12)
      k_proj<<<313,256,0,stream>>>(Hs(nxt,2), pk_proj, proj_b, out + (size_t)(s-12)*N_NODESC*64, xdec);
  }
}

// Round 19
// 3364.844 us; speedup vs baseline: 1.1864x; 1.1864x over previous
//
#include <hip/hip_runtime.h>

#define N_NODESC 20000
#define N_EDGESC 640000

typedef _Float16 f16;
typedef __attribute__((ext_vector_type(4))) _Float16 f16x4;
typedef __attribute__((ext_vector_type(8))) _Float16 f16x8;
typedef __attribute__((ext_vector_type(4))) float f32x4;

__device__ __forceinline__ f32x4 mfma16(f16x8 a, f16x8 b, f32x4 c){
  return __builtin_amdgcn_mfma_f32_16x16x32_f16(a, b, c, 0, 0, 0);
}
__device__ __forceinline__ float sigm(float x){ return 1.f/(1.f+__expf(-x)); }
__device__ __forceinline__ float tanh_(float x){
  x = fminf(fmaxf(x, -15.f), 15.f);
  float e = __expf(-2.f*x);
  return (1.f - e)/(1.f + e);
}
__device__ __forceinline__ void stage16(const void* g, void* l){
  __builtin_amdgcn_global_load_lds((const __attribute__((address_space(1))) unsigned int*)g,
                                   (__attribute__((address_space(3))) unsigned int*)l, 16, 0, 0);
}
#define SB       __builtin_amdgcn_sched_barrier(0)
#define AS_VM(n) do{ asm volatile("s_waitcnt vmcnt(" #n ")" ::: "memory"); SB; }while(0)
#define BAR      do{ __builtin_amdgcn_s_barrier(); SB; }while(0)

// ---------------- CSR construction ----------------
__global__ __launch_bounds__(256) void k_hist(const int* __restrict__ dst, int* __restrict__ cnt){
  int e = blockIdx.x*256 + threadIdx.x;
  if(e < N_EDGESC) atomicAdd(&cnt[dst[e]], 1);
}

__global__ __launch_bounds__(256) void k_scanA(const int* __restrict__ cnt,
    int* __restrict__ row_ptr, int* __restrict__ btot){
  __shared__ int ws[4];
  int b = blockIdx.x, t = threadIdx.x;
  int i = b*256 + t;
  int v = (i < N_NODESC) ? cnt[i] : 0;
  int lane = t&63, wv = t>>6;
  int incl = v;
  #pragma unroll
  for(int off=1; off<64; off<<=1){ int u = __shfl_up(incl, off); if(lane>=off) incl += u; }
  if(lane==63) ws[wv] = incl;
  __syncthreads();
  int woff = 0;
  for(int k=0;k<wv;k++) woff += ws[k];
  if(i < N_NODESC) row_ptr[i] = woff + incl - v;
  if(t == 255) btot[b] = woff + incl;
}

__global__ __launch_bounds__(128) void k_scanB(const int* __restrict__ btot,
    int* __restrict__ boff, int* __restrict__ row_ptr){
  __shared__ int s[128];
  int t = threadIdx.x;
  int orig = (t < 79) ? btot[t] : 0;
  s[t] = orig;
  __syncthreads();
  #pragma unroll
  for(int off=1; off<128; off<<=1){
    int u = (t>=off) ? s[t-off] : 0;
    __syncthreads();
    s[t] += u;
    __syncthreads();
  }
  if(t < 79) boff[t] = s[t] - orig;
  if(t == 0) row_ptr[N_NODESC] = N_EDGESC;
}

__global__ __launch_bounds__(256) void k_scanC(const int* __restrict__ cnt,
    const int* __restrict__ boff, int* __restrict__ row_ptr,
    float* __restrict__ deg_inv, float* __restrict__ deg_is){
  int i = blockIdx.x*256 + threadIdx.x;
  if(i >= N_NODESC) return;
  row_ptr[i] += boff[blockIdx.x];
  float d = (float)(cnt[i] + 1);
  deg_inv[i] = 1.f/d;
  deg_is[i]  = rsqrtf(d);
}

__global__ __launch_bounds__(256) void k_fill(const int* __restrict__ src, const int* __restrict__ dst,
    const int* __restrict__ row_ptr, int* __restrict__ cursor, const float* __restrict__ deg_is,
    int2* __restrict__ ev){
  int e = blockIdx.x*256 + threadIdx.x;
  if(e >= N_EDGESC) return;
  int d = dst[e], s = src[e];
  int p = atomicAdd(&cursor[d], 1);
  int2 v;
  v.x = s;
  v.y = __float_as_int(deg_is[s]*deg_is[d]);
  ev[row_ptr[d] + p] = v;
}

__global__ __launch_bounds__(256) void k_cvt(const float* __restrict__ x, f16* __restrict__ o, int n4){
  int i = blockIdx.x*256 + threadIdx.x;
  if(i >= n4) return;
  f32x4 v = *(const f32x4*)(x + (size_t)i*4);
  *(f16x4*)(o + (size_t)i*4) = __builtin_convertvector(v, f16x4);
}

// weight packing: Bp[((kb*NO + c)*4 + g)*8 + i] = B[k = kb*32 + g*8 + i][c]
__global__ __launch_bounds__(256) void k_pack(const float* __restrict__ w, f16* __restrict__ dstp,
    int K, int NO, int trans){
  int t = blockIdx.x*256 + threadIdx.x;
  if(t >= K*NO) return;
  int i = t&7, g = (t>>3)&3, rest = t>>5;
  int c = rest % NO, kb = rest / NO;
  int k = kb*32 + g*8 + i;
  float v = trans ? w[(size_t)c*K + k] : w[(size_t)k*NO + c];
  dstp[t] = (f16)v;
}

// ---------------- aggregation ----------------
__global__ __launch_bounds__(256) void k_agg64(const f16* __restrict__ x,
    const int* __restrict__ row_ptr, const int2* __restrict__ ev,
    const float* __restrict__ deg_inv, f16* __restrict__ O){
  int n = (blockIdx.x*256 + threadIdx.x)>>6;
  int c = threadIdx.x&63;
  if(n >= N_NODESC) return;
  float acc = deg_inv[n]*(float)x[(size_t)n*64 + c];
  int e0 = row_ptr[n], e1 = row_ptr[n+1];
  int e = e0;
  for(; e+4<=e1; e+=4){
    int2 a=ev[e], b=ev[e+1], cc=ev[e+2], d=ev[e+3];
    float v0=(float)x[(size_t)a.x*64+c],  v1=(float)x[(size_t)b.x*64+c];
    float v2=(float)x[(size_t)cc.x*64+c], v3=(float)x[(size_t)d.x*64+c];
    acc += __int_as_float(a.y)*v0 + __int_as_float(b.y)*v1
         + __int_as_float(cc.y)*v2 + __int_as_float(d.y)*v3;
  }
  for(; e<e1; e++){ int2 a=ev[e]; acc += __int_as_float(a.y)*(float)x[(size_t)a.x*64+c]; }
  O[(size_t)n*64+c] = (f16)acc;
}

// agg256 (R17 winner) + 8-deep unroll
__global__ __launch_bounds__(256) void k_agg256(const f16* __restrict__ x1,
    const int* __restrict__ row_ptr, const int2* __restrict__ ev,
    const float* __restrict__ deg_inv, f16* __restrict__ O){
  int n = (blockIdx.x*256 + threadIdx.x)>>6;
  int lane = threadIdx.x&63;
  if(n >= N_NODESC) return;
  const f16x4* xv = (const f16x4*)x1;
  f32x4 acc = __builtin_convertvector(xv[(size_t)n*64 + lane], f32x4) * deg_inv[n];
  int e0 = row_ptr[n], e1 = row_ptr[n+1];
  int e = e0;
  for(; e+8<=e1; e+=8){
    int2 a=ev[e],  b=ev[e+1], c2=ev[e+2], d=ev[e+3];
    int2 a2=ev[e+4], b2=ev[e+5], c3=ev[e+6], d2=ev[e+7];
    f32x4 v0=__builtin_convertvector(xv[(size_t)a.x*64+lane],  f32x4);
    f32x4 v1=__builtin_convertvector(xv[(size_t)b.x*64+lane],  f32x4);
    f32x4 v2=__builtin_convertvector(xv[(size_t)c2.x*64+lane], f32x4);
    f32x4 v3=__builtin_convertvector(xv[(size_t)d.x*64+lane],  f32x4);
    f32x4 v4=__builtin_convertvector(xv[(size_t)a2.x*64+lane], f32x4);
    f32x4 v5=__builtin_convertvector(xv[(size_t)b2.x*64+lane], f32x4);
    f32x4 v6=__builtin_convertvector(xv[(size_t)c3.x*64+lane], f32x4);
    f32x4 v7=__builtin_convertvector(xv[(size_t)d2.x*64+lane], f32x4);
    acc += v0*__int_as_float(a.y);  acc += v1*__int_as_float(b.y);
    acc += v2*__int_as_float(c2.y); acc += v3*__int_as_float(d.y);
    acc += v4*__int_as_float(a2.y); acc += v5*__int_as_float(b2.y);
    acc += v6*__int_as_float(c3.y); acc += v7*__int_as_float(d2.y);
  }
  for(; e+4<=e1; e+=4){
    int2 a=ev[e], b=ev[e+1], c2=ev[e+2], d=ev[e+3];
    f32x4 v0=__builtin_convertvector(xv[(size_t)a.x*64+lane],  f32x4);
    f32x4 v1=__builtin_convertvector(xv[(size_t)b.x*64+lane],  f32x4);
    f32x4 v2=__builtin_convertvector(xv[(size_t)c2.x*64+lane], f32x4);
    f32x4 v3=__builtin_convertvector(xv[(size_t)d.x*64+lane],  f32x4);
    acc += v0*__int_as_float(a.y); acc += v1*__int_as_float(b.y);
    acc += v2*__int_as_float(c2.y); acc += v3*__int_as_float(d.y);
  }
  for(; e<e1; e++){ int2 a=ev[e];
    acc += __builtin_convertvector(xv[(size_t)a.x*64+lane], f32x4)*__int_as_float(a.y); }
  ((f16x4*)O)[(size_t)n*64+lane] = __builtin_convertvector(acc, f16x4);
}

// =============== coalesced + swizzled resident-tile GEMM kernels (R15/R17 winners) ===============
// LDS per plane: [row][32 slots x 16B]; global chunk c at slot s = c ^ (row&7).
// A-frag read (r, kb, q): addr = r*512 + ((kb*4+q)^(l15&7))*16.

// ---------------- GCN1: K=64 (128B rows), N=256 ----------------
__global__ __launch_bounds__(256) void k_gcn1(const f16* __restrict__ A,
    const f16* __restrict__ Bp, const float* __restrict__ bias, f16* __restrict__ C){
  __shared__ f16x8 ldsv[512];                  // 8KB
  char* lds = (char*)ldsv;
  const int tid = threadIdx.x, lane = tid&63, w = tid>>6, l15 = lane&15, q = lane>>4;
  const int m0 = blockIdx.x*64;
  #pragma unroll
  for(int i=0;i<2;i++){
    const int o = i*4096 + tid*16;
    const int row = o>>7, s = (o>>4)&7;
    const int c = s ^ (row&7);
    int rgs = m0 + row; if(rgs > N_NODESC-1) rgs = N_NODESC-1;
    stage16((const char*)A + (size_t)rgs*128 + c*16, lds + o);
  }
  AS_VM(0);
  BAR;
  f32x4 acc[4][4];
  #pragma unroll
  for(int rt=0;rt<4;rt++)
    #pragma unroll
    for(int ct=0;ct<4;ct++) acc[rt][ct] = (f32x4){0.f,0.f,0.f,0.f};
  const int l7 = l15&7;
  #pragma unroll
  for(int kb=0;kb<2;kb++){
    f16x8 bf[4];
    #pragma unroll
    for(int ct=0;ct<4;ct++){
      int c = w*64 + ct*16 + l15;
      bf[ct] = *(const f16x8*)(Bp + ((unsigned)(kb*256 + c)*4 + q)*8);
    }
    const int swz = ((kb*4+q) ^ l7)<<4;
    #pragma unroll
    for(int rt=0;rt<4;rt++){
      f16x8 ah = *(const f16x8*)(lds + (rt*16+l15)*128 + swz);
      #pragma unroll
      for(int ct=0;ct<4;ct++)
        acc[rt][ct] = mfma16(ah, bf[ct], acc[rt][ct]);
    }
  }
  #pragma unroll
  for(int rt=0;rt<4;rt++)
    #pragma unroll
    for(int ct=0;ct<4;ct++){
      int c = w*64 + ct*16 + l15;
      float bv = bias[c];
      #pragma unroll
      for(int j=0;j<4;j++){
        int r = m0 + rt*16 + q*4 + j;
        if(r < N_NODESC) C[(size_t)r*256 + c] = (f16)fmaxf(acc[rt][ct][j] + bv, 0.f);
      }
    }
}

// ---------------- GCN2: 256-thr, A resident (32KB), dist-2 B ----------
__global__ __launch_bounds__(256,3) void k_gcn2(const f16* __restrict__ A,
    const f16* __restrict__ Bp, const float* __restrict__ bias, f16* __restrict__ C){
  __shared__ f16x8 ldsv[2048];                 // 32KB
  char* lds = (char*)ldsv;
  const int tid = threadIdx.x, lane = tid&63, w = tid>>6, l15 = lane&15, q = lane>>4;
  const int m0 = blockIdx.x*64;
  #pragma unroll
  for(int i=0;i<8;i++){
    const int o = i*4096 + tid*16;
    const int row = o>>9, s = (o>>4)&31;
    const int c = s ^ (row&7);
    int rgs = m0 + row; if(rgs > N_NODESC-1) rgs = N_NODESC-1;
    stage16((const char*)A + (size_t)rgs*512 + c*16, lds + o);
  }
  f32x4 acc[4][4];
  #pragma unroll
  for(int rt=0;rt<4;rt++)
    #pragma unroll
    for(int ct=0;ct<4;ct++) acc[rt][ct] = (f32x4){0.f,0.f,0.f,0.f};
  f16x8 bf[3][4];
  const int cbase = w*64 + l15;
  #pragma unroll
  for(int s=0;s<2;s++)
    #pragma unroll
    for(int ct=0;ct<4;ct++)
      bf[s][ct] = *(const f16x8*)(Bp + ((unsigned)(s*256 + cbase + ct*16)*4 + q)*8);
  AS_VM(0);
  BAR;
  const int l7 = l15&7;
  #pragma unroll
  for(int kb=0;kb<8;kb++){
    const int s = kb%3;
    if(kb<6){
      const int ns = (kb+2)%3;
      #pragma unroll
      for(int ct=0;ct<4;ct++)
        bf[ns][ct] = *(const f16x8*)(Bp + ((unsigned)((kb+2)*256 + cbase + ct*16)*4 + q)*8);
    }
    const int swz = ((kb*4+q) ^ l7)<<4;
    __builtin_amdgcn_s_setprio(1);
    #pragma unroll
    for(int rt=0;rt<4;rt++){
      f16x8 ah = *(const f16x8*)(lds + (rt*16+l15)*512 + swz);
      #pragma unroll
      for(int ct=0;ct<4;ct++)
        acc[rt][ct] = mfma16(ah, bf[s][ct], acc[rt][ct]);
    }
    __builtin_amdgcn_s_setprio(0);
  }
  #pragma unroll
  for(int rt=0;rt<4;rt++)
    #pragma unroll
    for(int ct=0;ct<4;ct++){
      int c = cbase + ct*16;
      float bv = bias[c];
      #pragma unroll
      for(int j=0;j<4;j++){
        int r = m0 + rt*16 + q*4 + j;
        if(r < N_NODESC) C[(size_t)r*256 + c] = (f16)fmaxf(acc[rt][ct][j] + bv, 0.f);
      }
    }
}

// ---------------- fused GRU v13: R15 structure (256-thr) + ZH template ----------
template<int ZH>
__global__ __launch_bounds__(256,2) void k_gru(
    const f16* __restrict__ X, const f16* __restrict__ H, f16* __restrict__ Nh,
    const f16* __restrict__ Wi, const f16* __restrict__ Wh,
    const float* __restrict__ bih, const float* __restrict__ bhh){
  __shared__ f16x8 ldsv[4096];                 // 64KB: 2 planes x [row:64][32x16B]
  char* lds = (char*)ldsv;
  const int NB = 1252, QQ = NB>>3, RR = NB&7;  // 156, 4
  int bid = blockIdx.x;
  int xcd = bid & 7, jj = bid >> 3;
  int nid = (xcd < RR) ? xcd*(QQ+1) + jj : RR*(QQ+1) + (xcd-RR)*QQ + jj;
  const int m0 = (nid>>2)*64;
  const int cb = nid&3;
  const int tid = threadIdx.x, lane = tid&63, w = tid>>6, l15 = lane&15, q = lane>>4;
  const int cc = cb*64 + w*16 + l15;
  const f16* pl[2] = {X, H};
  #pragma unroll
  for(int i=0;i<(ZH?8:16);i++){
    const int o = i*4096 + tid*16;
    const int p = o>>15;
    const int rem = o & 32767;
    const int row = rem>>9, s = (rem>>4)&31;
    const int c = s ^ (row&7);
    int rgs = m0 + row; if(rgs > N_NODESC-1) rgs = N_NODESC-1;
    stage16((const char*)pl[p] + (size_t)rgs*512 + c*16, lds + o);
  }
  f32x4 acc[6][4];
  #pragma unroll
  for(int m=0;m<6;m++)
    #pragma unroll
    for(int rt=0;rt<4;rt++) acc[m][rt] = (f32x4){0.f,0.f,0.f,0.f};
  const unsigned wbase = (unsigned)cc*32 + q*8;   // f16 units; +gate*8192 +kb*24576
  f16x8 bi[3][3], bh[3][3];                       // ring: slot = kb%3
  #pragma unroll
  for(int s=0;s<2;s++){
    unsigned wo = wbase + (unsigned)s*24576u;
    bi[s][0] = *(const f16x8*)(Wi + wo);
    bi[s][1] = *(const f16x8*)(Wi + wo + 8192);
    bi[s][2] = *(const f16x8*)(Wi + wo + 16384);
    if(!ZH){
      bh[s][0] = *(const f16x8*)(Wh + wo);
      bh[s][1] = *(const f16x8*)(Wh + wo + 8192);
      bh[s][2] = *(const f16x8*)(Wh + wo + 16384);
    }
  }
  AS_VM(0);
  BAR;
  const int l7 = l15&7;
  #pragma unroll
  for(int kb=0;kb<8;kb++){
    const int s = kb%3;
    if(kb<6){
      const int ns = (kb+2)%3;
      unsigned wo = wbase + (unsigned)(kb+2)*24576u;
      bi[ns][0] = *(const f16x8*)(Wi + wo);
      bi[ns][1] = *(const f16x8*)(Wi + wo + 8192);
      bi[ns][2] = *(const f16x8*)(Wi + wo + 16384);
      if(!ZH){
        bh[ns][0] = *(const f16x8*)(Wh + wo);
        bh[ns][1] = *(const f16x8*)(Wh + wo + 8192);
        bh[ns][2] = *(const f16x8*)(Wh + wo + 16384);
      }
    }
    const int swz = ((kb*4+q) ^ l7)<<4;
    __builtin_amdgcn_s_setprio(1);
    #pragma unroll
    for(int rt=0;rt<4;rt++){
      const int ro = (rt*16+l15)*512 + swz;
      f16x8 ax = *(const f16x8*)(lds + ro);
      acc[0][rt] = mfma16(ax, bi[s][0], acc[0][rt]);
      acc[1][rt] = mfma16(ax, bi[s][1], acc[1][rt]);
      acc[2][rt] = mfma16(ax, bi[s][2], acc[2][rt]);
      if(!ZH){
        f16x8 ah = *(const f16x8*)(lds + 32768 + ro);
        acc[3][rt] = mfma16(ah, bh[s][0], acc[3][rt]);
        acc[4][rt] = mfma16(ah, bh[s][1], acc[4][rt]);
        acc[5][rt] = mfma16(ah, bh[s][2], acc[5][rt]);
      }
    }
    __builtin_amdgcn_s_setprio(0);
  }
  float bir=bih[cc], biz=bih[cc+256], bin=bih[cc+512];
  float bhr=bhh[cc], bhz=bhh[cc+256], bhn=bhh[cc+512];
  const int hcc = (cc>>3);
  const int hlo = (cc&7)*2;
  #pragma unroll
  for(int rt=0;rt<4;rt++){
    #pragma unroll
    for(int j=0;j<4;j++){
      int r = rt*16 + q*4 + j;
      int grow = m0 + r;
      if(grow < N_NODESC){
        float ir=acc[0][rt][j], iz=acc[1][rt][j], in_=acc[2][rt][j];
        float hr = ZH ? 0.f : acc[3][rt][j];
        float hz = ZH ? 0.f : acc[4][rt][j];
        float hn = ZH ? 0.f : acc[5][rt][j];
        float rgt = sigm(ir+bir + hr+bhr);
        float zg = sigm(iz+biz + hz+bhz);
        float ng = tanh_(in_+bin + rgt*(hn+bhn));
        float ho = ZH ? 0.f
          : (float)*(const f16*)(lds + 32768 + r*512 + ((hcc ^ (r&7))<<4) + hlo);
        float v = (1.f-zg)*ng + zg*ho;
        Nh[(size_t)grow*256 + cc] = (f16)v;
      }
    }
  }
}

// ---------------- projection: A resident (32KB), dist-2 B; f32 out + f16 feedback ----------
__global__ __launch_bounds__(256,4) void k_proj(const f16* __restrict__ A,
    const f16* __restrict__ Bp, const float* __restrict__ bias,
    float* __restrict__ C, f16* __restrict__ Cf16){
  __shared__ f16x8 ldsv[2048];                 // 32KB
  char* lds = (char*)ldsv;
  const int tid = threadIdx.x, lane = tid&63, w = tid>>6, l15 = lane&15, q = lane>>4;
  const int m0 = blockIdx.x*64;
  const int cc = w*16 + l15;
  #pragma unroll
  for(int i=0;i<8;i++){
    const int o = i*4096 + tid*16;
    const int row = o>>9, s = (o>>4)&31;
    const int c = s ^ (row&7);
    int rgs = m0 + row; if(rgs > N_NODESC-1) rgs = N_NODESC-1;
    stage16((const char*)A + (size_t)rgs*512 + c*16, lds + o);
  }
  f32x4 acc[4];
  #pragma unroll
  for(int rt=0;rt<4;rt++) acc[rt] = (f32x4){0.f,0.f,0.f,0.f};
  f16x8 bf[3];
  bf[0] = *(const f16x8*)(Bp + ((unsigned)(0*64 + cc)*4 + q)*8);
  bf[1] = *(const f16x8*)(Bp + ((unsigned)(1*64 + cc)*4 + q)*8);
  AS_VM(0);
  BAR;
  const int l7 = l15&7;
  #pragma unroll
  for(int kb=0;kb<8;kb++){
    const int s = kb%3;
    if(kb<6)
      bf[(kb+2)%3] = *(const f16x8*)(Bp + ((unsigned)((kb+2)*64 + cc)*4 + q)*8);
    const int swz = ((kb*4+q) ^ l7)<<4;
    #pragma unroll
    for(int rt=0;rt<4;rt++){
      f16x8 ah = *(const f16x8*)(lds + (rt*16+l15)*512 + swz);
      acc[rt] = mfma16(ah, bf[s], acc[rt]);
    }
  }
  #pragma unroll
  for(int rt=0;rt<4;rt++){
    float bv = bias[cc];
    #pragma unroll
    for(int j=0;j<4;j++){
      int r = m0 + rt*16 + q*4 + j;
      if(r < N_NODESC){
        float v = acc[rt][j] + bv;
        C[(size_t)r*64 + cc] = v;
        Cf16[(size_t)r*64 + cc] = (f16)v;
      }
    }
  }
}

// ---------------- launcher ----------------
extern "C" void kernel_launch(void* const* d_in, const int* in_sizes, int n_in,
                              void* d_out, int out_size, void* d_ws, size_t ws_size,
                              hipStream_t stream){
  const float* x_seq  = (const float*)d_in[0];
  const int*   srcp   = (const int*)  d_in[1];
  const int*   dstp   = (const int*)  d_in[2];
  const float* gcn1_w = (const float*)d_in[3];
  const float* gcn1_b = (const float*)d_in[4];
  const float* gcn2_w = (const float*)d_in[5];
  const float* gcn2_b = (const float*)d_in[6];
  const float* proj_w = (const float*)d_in[7];
  const float* proj_b = (const float*)d_in[8];
  const float* wih[3] = {(const float*)d_in[9],  (const float*)d_in[13], (const float*)d_in[17]};
  const float* whh[3] = {(const float*)d_in[10], (const float*)d_in[14], (const float*)d_in[18]};
  const float* bih[3] = {(const float*)d_in[11], (const float*)d_in[15], (const float*)d_in[19]};
  const float* bhh[3] = {(const float*)d_in[12], (const float*)d_in[16], (const float*)d_in[20]};
  float* out = (float*)d_out;

  const size_t NP = (size_t)N_NODESC*256;
  char* p = (char*)d_ws;
  auto alloc = [&](size_t bytes)->char*{ char* r = p; p += (bytes + 255) & ~(size_t)255; return r; };
  int*   deg_cnt = (int*)  alloc((size_t)2*N_NODESC*4);
  int*   cursor  = deg_cnt + N_NODESC;
  int*   row_ptr = (int*)  alloc((size_t)(N_NODESC+1)*4);
  float* deg_inv = (float*)alloc((size_t)N_NODESC*4);
  float* deg_is  = (float*)alloc((size_t)N_NODESC*4);
  int*   btot    = (int*)  alloc((size_t)128*4);
  int*   boff    = (int*)  alloc((size_t)128*4);
  int2*  ev      = (int2*) alloc((size_t)N_EDGESC*8);
  f16* xf16 = (f16*)alloc((size_t)12*N_NODESC*64*2);
  f16* xdec = (f16*)alloc((size_t)N_NODESC*64*2);
  f16* z64  = (f16*)alloc((size_t)N_NODESC*64*2);
  f16* x1   = (f16*)alloc(NP*2);
  f16* xa   = (f16*)alloc(NP*2);
  f16* hbuf = (f16*)alloc((size_t)2*3*NP*2);     // [slot][gru][N*256] — no memset (ZH path)
  f16* pk_gcn1 = (f16*)alloc((size_t)64*256*2);
  f16* pk_gcn2 = (f16*)alloc((size_t)256*256*2);
  f16* pk_proj = (f16*)alloc((size_t)256*64*2);
  f16* pk_wi[3]; f16* pk_wh[3];
  for(int i=0;i<3;i++){ pk_wi[i]=(f16*)alloc((size_t)256*768*2); pk_wh[i]=(f16*)alloc((size_t)256*768*2); }

  hipMemsetAsync(deg_cnt, 0, (size_t)2*N_NODESC*4, stream);

  k_hist <<<2500,256,0,stream>>>(dstp, deg_cnt);
  k_scanA<<<79,  256,0,stream>>>(deg_cnt, row_ptr, btot);
  k_scanB<<<1,   128,0,stream>>>(btot, boff, row_ptr);
  k_scanC<<<79,  256,0,stream>>>(deg_cnt, boff, row_ptr, deg_inv, deg_is);
  k_fill <<<2500,256,0,stream>>>(srcp, dstp, row_ptr, cursor, deg_is, ev);
  k_cvt  <<<15000,256,0,stream>>>(x_seq, xf16, 12*N_NODESC*64/4);

  k_pack<<<64, 256,0,stream>>>(gcn1_w, pk_gcn1, 64, 256, 0);
  k_pack<<<256,256,0,stream>>>(gcn2_w, pk_gcn2, 256,256, 0);
  k_pack<<<64, 256,0,stream>>>(proj_w, pk_proj, 256, 64, 0);
  for(int i=0;i<3;i++){
    k_pack<<<768,256,0,stream>>>(wih[i], pk_wi[i], 256, 768, 1);
    k_pack<<<768,256,0,stream>>>(whh[i], pk_wh[i], 256, 768, 1);
  }

  auto Hs = [&](int slot, int g)->f16*{ return hbuf + ((size_t)(slot*3+g))*NP; };

  for(int s=0; s<18; s++){
    const f16* xt;
    if(s < 12)       xt = xf16 + (size_t)s*N_NODESC*64;
    else if(s == 12) xt = xf16 + (size_t)11*N_NODESC*64;
    else             xt = xdec;
    int cur = s&1, nxt = cur^1;

    k_agg64 <<<5000,256,0,stream>>>(xt, row_ptr, ev, deg_inv, z64);
    k_gcn1  <<<313, 256,0,stream>>>(z64, pk_gcn1, gcn1_b, x1);
    k_agg256<<<5000,256,0,stream>>>(x1, row_ptr, ev, deg_inv, xa);
    k_gcn2  <<<313, 256,0,stream>>>(xa, pk_gcn2, gcn2_b, xa);

    if(s == 0){
      k_gru<1><<<1252,256,0,stream>>>(xa,        Hs(cur,0), Hs(nxt,0), pk_wi[0], pk_wh[0], bih[0], bhh[0]);
      k_gru<1><<<1252,256,0,stream>>>(Hs(nxt,0), Hs(cur,1), Hs(nxt,1), pk_wi[1], pk_wh[1], bih[1], bhh[1]);
      k_gru<1><<<1252,256,0,stream>>>(Hs(nxt,1), Hs(cur,2), Hs(nxt,2), pk_wi[2], pk_wh[2], bih[2], bhh[2]);
    } else {
      k_gru<0><<<1252,256,0,stream>>>(xa,        Hs(cur,0), Hs(nxt,0), pk_wi[0], pk_wh[0], bih[0], bhh[0]);
      k_gru<0><<<1252,256,0,stream>>>(Hs(nxt,0), Hs(cur,1), Hs(nxt,1), pk_wi[1], pk_wh[1], bih[1], bhh[1]);
      k_gru<0><<<1252,256,0,stream>>>(Hs(nxt,1), Hs(cur,2), Hs(nxt,2), pk_wi[2], pk_wh[2], bih[2], bhh[2]);
    }

    if(s >= 12)
      k_proj<<<313,256,0,stream>>>(Hs(nxt,2), pk_proj, proj_b, out + (size_t)(s-12)*N_NODESC*64, xdec);
  }
}